// Round 5
// baseline (1015.464 us; speedup 1.0000x reference)
//
#include <hip/hip_runtime.h>
#include <stdint.h>

// Problem constants
#define G 8
#define H 512
#define I_RAW 1028
#define I_PAD 1056          // padded K for the input GEMM (multiple of 32)
#define BB 128              // batch
#define TT 64               // seq len
#define GH (G*H)            // 4096
#define G3H (G*3*H)         // 12288
#define M_TOT (BB*TT)       // 8192
#define N3H (3*H)           // 1536

typedef __attribute__((ext_vector_type(8))) short bf16x8;
typedef __attribute__((ext_vector_type(4))) float f32x4;
typedef __attribute__((ext_vector_type(4))) unsigned short u16x4;

__device__ __forceinline__ unsigned short f2bf(float f) {
  unsigned int u = __float_as_uint(f);
  u += 0x7fffu + ((u >> 16) & 1u);   // round-to-nearest-even
  return (unsigned short)(u >> 16);
}
__device__ __forceinline__ float bf2f(unsigned short h) {
  return __uint_as_float(((unsigned int)h) << 16);
}

// ---------------- pack kernels ----------------
__global__ void k_pack_x(const float* __restrict__ z, const float* __restrict__ a,
                         unsigned short* __restrict__ xb) {
  int idx = blockIdx.x * 256 + threadIdx.x;
  if (idx >= M_TOT * I_PAD) return;
  int m = idx / I_PAD, i = idx % I_PAD;
  int b = m >> 6, t = m & 63;
  float v = 0.f;
  if (i < 4)            v = a[((size_t)b * TT + t) * 4 + i];
  else if (i < I_RAW)   v = z[((size_t)b * TT + t) * 1024 + (i - 4)];
  xb[idx] = f2bf(v);
}

__global__ void k_pack_wih(const float* __restrict__ w, unsigned short* __restrict__ wb) {
  int idx = blockIdx.x * 256 + threadIdx.x;
  if (idx >= G * N3H * I_PAD) return;
  int gj = idx / I_PAD, i = idx % I_PAD;   // gj = g*1536 + j
  float v = (i < I_RAW) ? w[(size_t)gj * I_RAW + i] : 0.f;
  wb[idx] = f2bf(v);
}

__global__ void k_pack_whh(const float* __restrict__ w, unsigned short* __restrict__ wb) {
  int idx = blockIdx.x * 256 + threadIdx.x;
  if (idx >= G * N3H * H) return;
  wb[idx] = f2bf(w[idx]);
}

__global__ void k_init_h(const float* __restrict__ h, unsigned short* __restrict__ hb0,
                         int* __restrict__ barcnt) {
  int idx = blockIdx.x * 256 + threadIdx.x;
  if (idx < 8 * 32) barcnt[idx] = 0;           // barrier counters (128B-spaced)
  if (idx >= BB * GH) return;
  hb0[idx] = f2bf(h[idx]);
}

// ---------------- input-projection GEMM (time-chunked, tl-major rows) ----------------
// Chunk row rc = tl*128 + b (tl = t - t0). Each 128-row m-tile = one timestep.
// Output layout (lane-matched to k_scan): xp3[tl][b>>2][g][i][q(4)][j(4)] ushort,
// i.e. per (tl, batch-quad, g, col i): 16 ushorts = 32B; q=3 slot is padding.
#define LROW 80   // LDS row stride in bytes (64B data + 16B pad)

__launch_bounds__(256, 2)
__global__ void k_xproj(const unsigned short* __restrict__ xb,
                        const unsigned short* __restrict__ wihb,
                        unsigned short* __restrict__ xp3,
                        int t0) {
  __shared__ char lA[128 * LROW];
  __shared__ char lB[128 * LROW];
  int blk = blockIdx.x;
  int by = blk / (G3H / 128);       // m-tile = timestep tl
  int bx = blk % (G3H / 128);       // 96 n-tiles
  int m0 = by * 128, n0 = bx * 128;
  int tid = threadIdx.x;
  int lane = tid & 63, wave = tid >> 6;
  int wm = (wave >> 1) * 64, wn = (wave & 1) * 64;

  f32x4 acc[4][4] = {};

  for (int kt = 0; kt < I_PAD / 32; ++kt) {
    int k0 = kt * 32;
#pragma unroll
    for (int p = 0; p < 2; ++p) {
      int row = p * 64 + (tid >> 2);
      int c = (tid & 3) * 16;  // byte within 64B row
      int rc = m0 + row;                       // chunk row
      int b = rc & (BB - 1), tl = rc >> 7;     // batch, chunk-local t
      const char* srcA = (const char*)&xb[(size_t)(b * TT + t0 + tl) * I_PAD + k0] + c;
      *(uint4*)(lA + row * LROW + c) = *(const uint4*)srcA;
      const char* srcB = (const char*)&wihb[(size_t)(n0 + row) * I_PAD + k0] + c;
      *(uint4*)(lB + row * LROW + c) = *(const uint4*)srcB;
    }
    __syncthreads();

    bf16x8 af[4], bf[4];
#pragma unroll
    for (int mt = 0; mt < 4; ++mt) {
      int r = wm + mt * 16 + (lane & 15);
      af[mt] = *(const bf16x8*)(lA + r * LROW + ((lane >> 4) * 16));
    }
#pragma unroll
    for (int nt = 0; nt < 4; ++nt) {
      int r = wn + nt * 16 + (lane & 15);
      bf[nt] = *(const bf16x8*)(lB + r * LROW + ((lane >> 4) * 16));
    }
#pragma unroll
    for (int mt = 0; mt < 4; ++mt)
#pragma unroll
      for (int nt = 0; nt < 4; ++nt)
        acc[mt][nt] = __builtin_amdgcn_mfma_f32_16x16x32_bf16(af[mt], bf[nt], acc[mt][nt], 0, 0, 0);
    __syncthreads();
  }

  // epilogue: D[row][col], col = lane&15, row = (lane>>4)*4 + j  [m89-verified]
  // j-quad == batch-quad (tl-major rows) -> one 8B ushort4 store per (mt,nt).
#pragma unroll
  for (int mt = 0; mt < 4; ++mt)
#pragma unroll
    for (int nt = 0; nt < 4; ++nt) {
      int m = m0 + wm + mt * 16 + (lane >> 4) * 4;   // j=0 row
      int tl = m >> 7;
      int bq = (m & (BB - 1)) >> 2;
      int n = n0 + wn + nt * 16 + (lane & 15);
      int g = n / N3H;
      int rem = n - g * N3H;
      int q = rem >> 9;
      int i = rem & (H - 1);
      u16x4 v;
      v[0] = f2bf(acc[mt][nt][0]);
      v[1] = f2bf(acc[mt][nt][1]);
      v[2] = f2bf(acc[mt][nt][2]);
      v[3] = f2bf(acc[mt][nt][3]);
      size_t addr = ((((size_t)tl * (BB / 4) + bq) * G + g) * H + i) * 16 + q * 4;
      *(u16x4*)&xp3[addr] = v;
    }
}

// ---------------- persistent recurrent scan (cooperative) ----------------
// grid 256 = g(8, fastest -> XCD-pinned blk%8) x 32 i-tiles of 16 cols.
// 512 threads = 8 waves, wave w owns batch rows w*16..w*16+15.
// W_hh fragments for this wg's 48 cols staged ONCE in LDS; h_prev f32 in regs.
// Per step: h bf16 loads (L2) -> 48 MFMA -> gates -> h store -> per-g barrier;
// out f32 stores + next-step xp prefetch overlap the barrier spin.
__launch_bounds__(512, 2)
__global__ void k_scan(const unsigned short* __restrict__ xp3,
                       const unsigned short* __restrict__ whhb,
                       const float* __restrict__ b_ih,
                       const float* __restrict__ b_hh,
                       const float* __restrict__ hsrc, int hstride,
                       unsigned short* __restrict__ hbuf0,
                       unsigned short* __restrict__ hbuf1,
                       float* __restrict__ out,
                       int* __restrict__ barcnt,
                       int t0, int Tc) {
  __shared__ char wlds[48 * 1024];   // [q][kt][lane] 16B fragments, linear
  int blk = blockIdx.x;
  int g = blk & 7;
  int i0 = (blk >> 3) << 4;
  int tid = threadIdx.x, lane = tid & 63, wave = tid >> 6;
  const unsigned short* wg_w = whhb + (size_t)g * N3H * H;

  // stage W fragments: slot s = q*1024 + kt*64 + l
  for (int s = tid; s < 3072; s += 512) {
    int q = s >> 10, kt = (s >> 6) & 15, l = s & 63;
    int j = q * H + i0 + (l & 15);
    int k = kt * 32 + (l >> 4) * 8;
    *(bf16x8*)(wlds + (size_t)s * 16) = *(const bf16x8*)&wg_w[(size_t)j * H + k];
  }

  int ic = lane & 15;
  int i = i0 + ic;
  float brc = b_ih[g * N3H + 0 * H + i] + b_hh[g * N3H + 0 * H + i];
  float bzc = b_ih[g * N3H + 1 * H + i] + b_hh[g * N3H + 1 * H + i];
  float bin = b_ih[g * N3H + 2 * H + i];
  float bhn = b_hh[g * N3H + 2 * H + i];

  // h_prev f32 in regs: rows b_j = wave*16 + (lane>>4)*4 + j, col i
  float hprev[4];
#pragma unroll
  for (int j = 0; j < 4; ++j) {
    int b = wave * 16 + (lane >> 4) * 4 + j;
    hprev[j] = hsrc[(size_t)b * hstride + g * H + i];
  }

  int arow = wave * 16 + (lane & 15);   // A-fragment batch row
  int akoff = (lane >> 4) * 8;
  int* cnt = &barcnt[g * 32];

  // per-lane xp base: (bq, g, i) fixed; per-tl stride = 32*8*512*16 ushorts
  int bq = wave * 4 + (lane >> 4);
  const unsigned short* xbase = xp3 + ((((size_t)bq) * G + g) * H + i) * 16;
  const size_t xstep = (size_t)(BB / 4) * G * H * 16;

  __syncthreads();   // wlds ready

  u16x4 xq[3];
#pragma unroll
  for (int q = 0; q < 3; ++q) xq[q] = *(const u16x4*)(xbase + q * 4);

  for (int tl = 0; tl < Tc; ++tl) {
    int t = t0 + tl;
    const unsigned short* hin = (t & 1) ? hbuf1 : hbuf0;
    unsigned short* hout = (t & 1) ? hbuf0 : hbuf1;

    // A loads (h rows), independent -> issued as a batch
    bf16x8 af[16];
#pragma unroll
    for (int kt = 0; kt < 16; ++kt)
      af[kt] = *(const bf16x8*)&hin[(size_t)arow * GH + g * H + kt * 32 + akoff];

    f32x4 acc[3] = {};
#pragma unroll
    for (int kt = 0; kt < 16; ++kt) {
#pragma unroll
      for (int q = 0; q < 3; ++q) {
        bf16x8 wf = *(const bf16x8*)(wlds + ((size_t)(q * 16 + kt) * 64 + lane) * 16);
        acc[q] = __builtin_amdgcn_mfma_f32_16x16x32_bf16(af[kt], wf, acc[q], 0, 0, 0);
      }
    }

    // fused GRU gates; rows b = wave*16 + (lane>>4)*4 + j, col i
    float hn4[4];
#pragma unroll
    for (int j = 0; j < 4; ++j) {
      int b = wave * 16 + (lane >> 4) * 4 + j;
      float xr = bf2f(xq[0][j]);
      float xz = bf2f(xq[1][j]);
      float xn = bf2f(xq[2][j]);
      float r = 1.f / (1.f + __expf(-(xr + acc[0][j] + brc)));
      float u = 1.f / (1.f + __expf(-(xz + acc[1][j] + bzc)));
      float nn = xn + bin + r * (acc[2][j] + bhn);
      float th = 1.f - 2.f / (1.f + __expf(2.f * nn));   // tanh
      float hnew = (1.f - u) * th + u * hprev[j];
      hprev[j] = hnew;
      hn4[j] = hnew;
      hout[(size_t)b * GH + g * H + i] = f2bf(hnew);   // h store (pre-signal)
    }

    // drain h stores, then signal
    asm volatile("s_waitcnt vmcnt(0)" ::: "memory");
    __syncthreads();
    if (tid == 0)
      __hip_atomic_fetch_add(cnt, 1, __ATOMIC_RELAXED, __HIP_MEMORY_SCOPE_AGENT);

    // overlap with barrier: out f32 stores + next-step xp prefetch
#pragma unroll
    for (int j = 0; j < 4; ++j) {
      int b = wave * 16 + (lane >> 4) * 4 + j;
      out[((size_t)b * TT + t) * GH + g * H + i] = hn4[j];
    }
    if (tl + 1 < Tc) {
      const unsigned short* xb2 = xbase + (size_t)(tl + 1) * xstep;
#pragma unroll
      for (int q = 0; q < 3; ++q) xq[q] = *(const u16x4*)(xb2 + q * 4);
    }

    if (tid == 0 && tl != Tc - 1) {
      int target = 32 * (t + 1);
      while (__hip_atomic_load(cnt, __ATOMIC_ACQUIRE, __HIP_MEMORY_SCOPE_AGENT) < target)
        __builtin_amdgcn_s_sleep(1);
    }
    __syncthreads();
  }
}

// ---------------- launch ----------------
extern "C" void kernel_launch(void* const* d_in, const int* in_sizes, int n_in,
                              void* d_out, int out_size, void* d_ws, size_t ws_size,
                              hipStream_t stream) {
  const float* z    = (const float*)d_in[0];
  const float* a    = (const float*)d_in[1];
  const float* h0   = (const float*)d_in[2];
  const float* Wih  = (const float*)d_in[3];
  const float* Whh  = (const float*)d_in[4];
  const float* bih  = (const float*)d_in[5];
  const float* bhh  = (const float*)d_in[6];
  float* out = (float*)d_out;

  // workspace layout (bytes)
  char* ws = (char*)d_ws;
  const size_t XB_OFF  = 0;                                     // 17.3 MB
  const size_t WIH_OFF = XB_OFF  + (size_t)M_TOT * I_PAD * 2;   // 26.0 MB
  const size_t WHH_OFF = WIH_OFF + (size_t)G * N3H * I_PAD * 2; // 12.6 MB
  const size_t HB_OFF  = WHH_OFF + (size_t)G * N3H * H * 2;     // 2 x 1 MB bf16 h ping-pong
  const size_t BAR_OFF = HB_OFF  + 2 * (size_t)BB * GH * 2;     // 1 KB barrier counters
  const size_t XP_OFF  = BAR_OFF + 1024;
  const size_t FIXED   = XP_OFF;

  // adaptive time-chunking: largest power-of-2 Tc<=64 whose xp3 chunk fits ws
  const size_t XP_ROW = (size_t)(BB / 4) * G * H * 16 * 2;   // bytes per time step = 4 MiB
  int tcShift = 6;
  while (tcShift > 0 && FIXED + (XP_ROW << tcShift) > ws_size) --tcShift;
  const int Tc = 1 << tcShift;

  unsigned short* xb   = (unsigned short*)(ws + XB_OFF);
  unsigned short* wihb = (unsigned short*)(ws + WIH_OFF);
  unsigned short* whhb = (unsigned short*)(ws + WHH_OFF);
  unsigned short* hb   = (unsigned short*)(ws + HB_OFF);
  int*            barcnt = (int*)(ws + BAR_OFF);
  unsigned short* xp3  = (unsigned short*)(ws + XP_OFF);

  unsigned short* hbuf0 = hb;
  unsigned short* hbuf1 = hb + (size_t)BB * GH;

  // pack
  {
    int n = M_TOT * I_PAD;
    k_pack_x<<<(n + 255) / 256, 256, 0, stream>>>(z, a, xb);
  }
  {
    int n = G * N3H * I_PAD;
    k_pack_wih<<<(n + 255) / 256, 256, 0, stream>>>(Wih, wihb);
  }
  {
    int n = G * N3H * H;
    k_pack_whh<<<(n + 255) / 256, 256, 0, stream>>>(Whh, whhb);
  }
  {
    int n = BB * GH;
    k_init_h<<<(n + 255) / 256, 256, 0, stream>>>(h0, hbuf0, barcnt);
  }

  // time-chunked: xproj GEMM for chunk, then one persistent scan kernel
  for (int t0 = 0; t0 < TT; t0 += Tc) {
    k_xproj<<<Tc * (G3H / 128), 256, 0, stream>>>(xb, wihb, xp3, t0);

    const float* hsrc = (t0 == 0) ? h0 : (const float*)(out + (size_t)(t0 - 1) * GH);
    int hstride = (t0 == 0) ? GH : TT * GH;
    int t0v = t0, tcv = Tc;
    void* args[] = { (void*)&xp3, (void*)&whhb, (void*)&bih, (void*)&bhh,
                     (void*)&hsrc, (void*)&hstride, (void*)&hbuf0, (void*)&hbuf1,
                     (void*)&out, (void*)&barcnt, (void*)&t0v, (void*)&tcv };
    hipLaunchCooperativeKernel((void*)k_scan, dim3(256), dim3(512), args, 0, stream);
  }
}

// Round 6
// 922.030 us; speedup vs baseline: 1.1013x; 1.1013x over previous
//
#include <hip/hip_runtime.h>
#include <stdint.h>

// Problem constants
#define G 8
#define H 512
#define I_RAW 1028
#define I_PAD 1056          // padded K for the input GEMM (multiple of 32)
#define BB 128              // batch
#define TT 64               // seq len
#define GH (G*H)            // 4096
#define G3H (G*3*H)         // 12288
#define M_TOT (BB*TT)       // 8192
#define N3H (3*H)           // 1536

typedef __attribute__((ext_vector_type(8))) short bf16x8;
typedef __attribute__((ext_vector_type(4))) float f32x4;
typedef __attribute__((ext_vector_type(4))) unsigned short u16x4;

__device__ __forceinline__ unsigned short f2bf(float f) {
  unsigned int u = __float_as_uint(f);
  u += 0x7fffu + ((u >> 16) & 1u);   // round-to-nearest-even
  return (unsigned short)(u >> 16);
}
__device__ __forceinline__ float bf2f(unsigned short h) {
  return __uint_as_float(((unsigned int)h) << 16);
}

// ---------------- pack kernels ----------------
__global__ void k_pack_x(const float* __restrict__ z, const float* __restrict__ a,
                         unsigned short* __restrict__ xb) {
  int idx = blockIdx.x * 256 + threadIdx.x;
  if (idx >= M_TOT * I_PAD) return;
  int m = idx / I_PAD, i = idx % I_PAD;
  int b = m >> 6, t = m & 63;
  float v = 0.f;
  if (i < 4)            v = a[((size_t)b * TT + t) * 4 + i];
  else if (i < I_RAW)   v = z[((size_t)b * TT + t) * 1024 + (i - 4)];
  xb[idx] = f2bf(v);
}

__global__ void k_pack_wih(const float* __restrict__ w, unsigned short* __restrict__ wb) {
  int idx = blockIdx.x * 256 + threadIdx.x;
  if (idx >= G * N3H * I_PAD) return;
  int gj = idx / I_PAD, i = idx % I_PAD;   // gj = g*1536 + j
  float v = (i < I_RAW) ? w[(size_t)gj * I_RAW + i] : 0.f;
  wb[idx] = f2bf(v);
}

__global__ void k_pack_whh(const float* __restrict__ w, unsigned short* __restrict__ wb) {
  int idx = blockIdx.x * 256 + threadIdx.x;
  if (idx >= G * N3H * H) return;
  wb[idx] = f2bf(w[idx]);
}

__global__ void k_init_h(const float* __restrict__ h, unsigned short* __restrict__ hb0,
                         int* __restrict__ flags) {
  int idx = blockIdx.x * 256 + threadIdx.x;
  if (idx < 8 * 32) flags[idx] = 0;            // per-wg step flags [g][wg-in-g]
  if (idx >= BB * GH) return;
  hb0[idx] = f2bf(h[idx]);
}

// ---------------- input-projection GEMM (time-chunked, tl-major rows) ----------------
// Chunk row rc = tl*128 + b (tl = t - t0). Each 128-row m-tile = one timestep.
// Output layout (lane-matched to k_scan): xp3[tl][b>>2][g][i][q(4)][j(4)] ushort,
// i.e. per (tl, batch-quad, g, col i): 16 ushorts = 32B; q=3 slot is padding.
#define LROW 80   // LDS row stride in bytes (64B data + 16B pad)

__launch_bounds__(256, 2)
__global__ void k_xproj(const unsigned short* __restrict__ xb,
                        const unsigned short* __restrict__ wihb,
                        unsigned short* __restrict__ xp3,
                        int t0) {
  __shared__ char lA[128 * LROW];
  __shared__ char lB[128 * LROW];
  int blk = blockIdx.x;
  int by = blk / (G3H / 128);       // m-tile = timestep tl
  int bx = blk % (G3H / 128);       // 96 n-tiles
  int m0 = by * 128, n0 = bx * 128;
  int tid = threadIdx.x;
  int lane = tid & 63, wave = tid >> 6;
  int wm = (wave >> 1) * 64, wn = (wave & 1) * 64;

  f32x4 acc[4][4] = {};

  for (int kt = 0; kt < I_PAD / 32; ++kt) {
    int k0 = kt * 32;
#pragma unroll
    for (int p = 0; p < 2; ++p) {
      int row = p * 64 + (tid >> 2);
      int c = (tid & 3) * 16;  // byte within 64B row
      int rc = m0 + row;                       // chunk row
      int b = rc & (BB - 1), tl = rc >> 7;     // batch, chunk-local t
      const char* srcA = (const char*)&xb[(size_t)(b * TT + t0 + tl) * I_PAD + k0] + c;
      *(uint4*)(lA + row * LROW + c) = *(const uint4*)srcA;
      const char* srcB = (const char*)&wihb[(size_t)(n0 + row) * I_PAD + k0] + c;
      *(uint4*)(lB + row * LROW + c) = *(const uint4*)srcB;
    }
    __syncthreads();

    bf16x8 af[4], bf[4];
#pragma unroll
    for (int mt = 0; mt < 4; ++mt) {
      int r = wm + mt * 16 + (lane & 15);
      af[mt] = *(const bf16x8*)(lA + r * LROW + ((lane >> 4) * 16));
    }
#pragma unroll
    for (int nt = 0; nt < 4; ++nt) {
      int r = wn + nt * 16 + (lane & 15);
      bf[nt] = *(const bf16x8*)(lB + r * LROW + ((lane >> 4) * 16));
    }
#pragma unroll
    for (int mt = 0; mt < 4; ++mt)
#pragma unroll
      for (int nt = 0; nt < 4; ++nt)
        acc[mt][nt] = __builtin_amdgcn_mfma_f32_16x16x32_bf16(af[mt], bf[nt], acc[mt][nt], 0, 0, 0);
    __syncthreads();
  }

  // epilogue: D[row][col], col = lane&15, row = (lane>>4)*4 + j  [m89-verified]
  // j-quad == batch-quad (tl-major rows) -> one 8B ushort4 store per (mt,nt).
#pragma unroll
  for (int mt = 0; mt < 4; ++mt)
#pragma unroll
    for (int nt = 0; nt < 4; ++nt) {
      int m = m0 + wm + mt * 16 + (lane >> 4) * 4;   // j=0 row
      int tl = m >> 7;
      int bq = (m & (BB - 1)) >> 2;
      int n = n0 + wn + nt * 16 + (lane & 15);
      int g = n / N3H;
      int rem = n - g * N3H;
      int q = rem >> 9;
      int i = rem & (H - 1);
      u16x4 v;
      v[0] = f2bf(acc[mt][nt][0]);
      v[1] = f2bf(acc[mt][nt][1]);
      v[2] = f2bf(acc[mt][nt][2]);
      v[3] = f2bf(acc[mt][nt][3]);
      size_t addr = ((((size_t)tl * (BB / 4) + bq) * G + g) * H + i) * 16 + q * 4;
      *(u16x4*)&xp3[addr] = v;
    }
}

// ---------------- persistent recurrent scan (cooperative) ----------------
// grid 256 = g(8, fastest -> XCD-pinned blk%8) x 32 i-tiles of 16 cols.
// 512 threads = 8 waves, wave w owns batch rows w*16..w*16+15.
// W_hh fragments for this wg's 48 cols staged ONCE in LDS; h_prev f32 in regs.
// Per step: h bf16 loads (L2) -> 48 MFMA -> gates -> h store -> per-g barrier.
// Barrier: per-wg flag store (relaxed, no RMW) + wave-parallel relaxed poll +
// ONE agent-acquire fence at exit (L1 inv). out-stores/xp-prefetch overlap it.
__launch_bounds__(512, 2)
__global__ void k_scan(const unsigned short* __restrict__ xp3,
                       const unsigned short* __restrict__ whhb,
                       const float* __restrict__ b_ih,
                       const float* __restrict__ b_hh,
                       const float* __restrict__ hsrc, int hstride,
                       unsigned short* __restrict__ hbuf0,
                       unsigned short* __restrict__ hbuf1,
                       float* __restrict__ out,
                       int* __restrict__ flags,
                       int t0, int Tc) {
  __shared__ char wlds[48 * 1024];   // [q][kt][lane] 16B fragments, linear
  int blk = blockIdx.x;
  int g = blk & 7;
  int wgi = blk >> 3;                // wg index within g: 0..31
  int i0 = wgi << 4;
  int tid = threadIdx.x, lane = tid & 63, wave = tid >> 6;
  const unsigned short* wg_w = whhb + (size_t)g * N3H * H;

  // stage W fragments: slot s = q*1024 + kt*64 + l
  for (int s = tid; s < 3072; s += 512) {
    int q = s >> 10, kt = (s >> 6) & 15, l = s & 63;
    int j = q * H + i0 + (l & 15);
    int k = kt * 32 + (l >> 4) * 8;
    *(bf16x8*)(wlds + (size_t)s * 16) = *(const bf16x8*)&wg_w[(size_t)j * H + k];
  }

  int ic = lane & 15;
  int i = i0 + ic;
  float brc = b_ih[g * N3H + 0 * H + i] + b_hh[g * N3H + 0 * H + i];
  float bzc = b_ih[g * N3H + 1 * H + i] + b_hh[g * N3H + 1 * H + i];
  float bin = b_ih[g * N3H + 2 * H + i];
  float bhn = b_hh[g * N3H + 2 * H + i];

  // h_prev f32 in regs: rows b_j = wave*16 + (lane>>4)*4 + j, col i
  float hprev[4];
#pragma unroll
  for (int j = 0; j < 4; ++j) {
    int b = wave * 16 + (lane >> 4) * 4 + j;
    hprev[j] = hsrc[(size_t)b * hstride + g * H + i];
  }

  int arow = wave * 16 + (lane & 15);   // A-fragment batch row
  int akoff = (lane >> 4) * 8;
  int* gflags = &flags[g * 32];

  // per-lane xp base: (bq, g, i) fixed; per-tl stride
  int bq = wave * 4 + (lane >> 4);
  const unsigned short* xbase = xp3 + ((((size_t)bq) * G + g) * H + i) * 16;
  const size_t xstep = (size_t)(BB / 4) * G * H * 16;

  __syncthreads();   // wlds ready

  u16x4 xq[3];
#pragma unroll
  for (int q = 0; q < 3; ++q) xq[q] = *(const u16x4*)(xbase + q * 4);

  for (int tl = 0; tl < Tc; ++tl) {
    int t = t0 + tl;
    const unsigned short* hin = (t & 1) ? hbuf1 : hbuf0;
    unsigned short* hout = (t & 1) ? hbuf0 : hbuf1;

    // A loads (h rows), independent -> issued as a batch
    bf16x8 af[16];
#pragma unroll
    for (int kt = 0; kt < 16; ++kt)
      af[kt] = *(const bf16x8*)&hin[(size_t)arow * GH + g * H + kt * 32 + akoff];

    f32x4 acc[3] = {};
#pragma unroll
    for (int kt = 0; kt < 16; ++kt) {
#pragma unroll
      for (int q = 0; q < 3; ++q) {
        bf16x8 wf = *(const bf16x8*)(wlds + ((size_t)(q * 16 + kt) * 64 + lane) * 16);
        acc[q] = __builtin_amdgcn_mfma_f32_16x16x32_bf16(af[kt], wf, acc[q], 0, 0, 0);
      }
    }

    // fused GRU gates; rows b = wave*16 + (lane>>4)*4 + j, col i
    float hn4[4];
#pragma unroll
    for (int j = 0; j < 4; ++j) {
      int b = wave * 16 + (lane >> 4) * 4 + j;
      float xr = bf2f(xq[0][j]);
      float xz = bf2f(xq[1][j]);
      float xn = bf2f(xq[2][j]);
      float r = 1.f / (1.f + __expf(-(xr + acc[0][j] + brc)));
      float u = 1.f / (1.f + __expf(-(xz + acc[1][j] + bzc)));
      float nn = xn + bin + r * (acc[2][j] + bhn);
      float th = 1.f - 2.f / (1.f + __expf(2.f * nn));   // tanh
      float hnew = (1.f - u) * th + u * hprev[j];
      hprev[j] = hnew;
      hn4[j] = hnew;
      hout[(size_t)b * GH + g * H + i] = f2bf(hnew);   // h store (pre-signal)
    }

    // drain h stores (all waves), then signal own flag (no RMW, no fence)
    asm volatile("s_waitcnt vmcnt(0)" ::: "memory");
    __syncthreads();
    if (tid == 0)
      __hip_atomic_store(&gflags[wgi], t + 1, __ATOMIC_RELAXED, __HIP_MEMORY_SCOPE_AGENT);

    // overlap with barrier: out f32 stores + next-step xp prefetch (into regs,
    // immune to the later L1 invalidate)
#pragma unroll
    for (int j = 0; j < 4; ++j) {
      int b = wave * 16 + (lane >> 4) * 4 + j;
      out[((size_t)b * TT + t) * GH + g * H + i] = hn4[j];
    }
    if (tl + 1 < Tc) {
      const unsigned short* xb2 = xbase + (size_t)(tl + 1) * xstep;
#pragma unroll
      for (int q = 0; q < 3; ++q) xq[q] = *(const u16x4*)(xb2 + q * 4);
    }

    if (tl != Tc - 1) {
      if (wave == 0) {
        // wave-parallel relaxed poll: lane l watches flag[l&31]
        int target = t + 1;
        for (;;) {
          int f = __hip_atomic_load(&gflags[lane & 31], __ATOMIC_RELAXED,
                                    __HIP_MEMORY_SCOPE_AGENT);
          if (__ballot(f >= target) == ~0ull) break;
          __builtin_amdgcn_s_sleep(1);
        }
        __builtin_amdgcn_fence(__ATOMIC_ACQUIRE, "agent");  // one L1 inv per step
      }
      __syncthreads();
    }
  }
}

// ---------------- launch ----------------
extern "C" void kernel_launch(void* const* d_in, const int* in_sizes, int n_in,
                              void* d_out, int out_size, void* d_ws, size_t ws_size,
                              hipStream_t stream) {
  const float* z    = (const float*)d_in[0];
  const float* a    = (const float*)d_in[1];
  const float* h0   = (const float*)d_in[2];
  const float* Wih  = (const float*)d_in[3];
  const float* Whh  = (const float*)d_in[4];
  const float* bih  = (const float*)d_in[5];
  const float* bhh  = (const float*)d_in[6];
  float* out = (float*)d_out;

  // workspace layout (bytes)
  char* ws = (char*)d_ws;
  const size_t XB_OFF  = 0;                                     // 17.3 MB
  const size_t WIH_OFF = XB_OFF  + (size_t)M_TOT * I_PAD * 2;   // 26.0 MB
  const size_t WHH_OFF = WIH_OFF + (size_t)G * N3H * I_PAD * 2; // 12.6 MB
  const size_t HB_OFF  = WHH_OFF + (size_t)G * N3H * H * 2;     // 2 x 1 MB bf16 h ping-pong
  const size_t BAR_OFF = HB_OFF  + 2 * (size_t)BB * GH * 2;     // 1 KB step flags
  const size_t XP_OFF  = BAR_OFF + 1024;
  const size_t FIXED   = XP_OFF;

  // adaptive time-chunking: largest power-of-2 Tc<=64 whose xp3 chunk fits ws
  const size_t XP_ROW = (size_t)(BB / 4) * G * H * 16 * 2;   // bytes per time step = 4 MiB
  int tcShift = 6;
  while (tcShift > 0 && FIXED + (XP_ROW << tcShift) > ws_size) --tcShift;
  const int Tc = 1 << tcShift;

  unsigned short* xb   = (unsigned short*)(ws + XB_OFF);
  unsigned short* wihb = (unsigned short*)(ws + WIH_OFF);
  unsigned short* whhb = (unsigned short*)(ws + WHH_OFF);
  unsigned short* hb   = (unsigned short*)(ws + HB_OFF);
  int*            flags = (int*)(ws + BAR_OFF);
  unsigned short* xp3  = (unsigned short*)(ws + XP_OFF);

  unsigned short* hbuf0 = hb;
  unsigned short* hbuf1 = hb + (size_t)BB * GH;

  // pack
  {
    int n = M_TOT * I_PAD;
    k_pack_x<<<(n + 255) / 256, 256, 0, stream>>>(z, a, xb);
  }
  {
    int n = G * N3H * I_PAD;
    k_pack_wih<<<(n + 255) / 256, 256, 0, stream>>>(Wih, wihb);
  }
  {
    int n = G * N3H * H;
    k_pack_whh<<<(n + 255) / 256, 256, 0, stream>>>(Whh, whhb);
  }
  {
    int n = BB * GH;
    k_init_h<<<(n + 255) / 256, 256, 0, stream>>>(h0, hbuf0, flags);
  }

  // time-chunked: xproj GEMM for chunk, then one persistent scan kernel
  for (int t0 = 0; t0 < TT; t0 += Tc) {
    k_xproj<<<Tc * (G3H / 128), 256, 0, stream>>>(xb, wihb, xp3, t0);

    const float* hsrc = (t0 == 0) ? h0 : (const float*)(out + (size_t)(t0 - 1) * GH);
    int hstride = (t0 == 0) ? GH : TT * GH;
    int t0v = t0, tcv = Tc;
    void* args[] = { (void*)&xp3, (void*)&whhb, (void*)&bih, (void*)&bhh,
                     (void*)&hsrc, (void*)&hstride, (void*)&hbuf0, (void*)&hbuf1,
                     (void*)&out, (void*)&flags, (void*)&t0v, (void*)&tcv };
    hipLaunchCooperativeKernel((void*)k_scan, dim3(256), dim3(512), args, 0, stream);
  }
}